// Round 1
// baseline (1895.308 us; speedup 1.0000x reference)
//
#include <hip/hip_runtime.h>
#include <math.h>

// Problem constants
#define BN 16
#define CIN 64
#define HH 128
#define WW 128
#define HWSZ (HH*WW)          // 16384
#define NC 80
#define KK 100

// Workspace layout (in floats)
#define WS_WT1   0
#define WT1_SZ   (3*64*9*64)                 // 110592
#define WS_CLS   (WS_WT1 + WT1_SZ)
#define CLS_SZ   (BN*NC*HWSZ)                // 20,971,520
#define WS_REG   (WS_CLS + CLS_SZ)
#define REG_SZ   (BN*2*HWSZ)
#define WS_WH    (WS_REG + REG_SZ)
#define WH_SZ    (BN*2*HWSZ)
#define WS_SC    (WS_WH + WH_SZ)             // scores_all
#define SC_SZ    (BN*HWSZ)
#define WS_CAT   (WS_SC + SC_SZ)             // int cats_all
#define CAT_SZ   (BN*HWSZ)
#define WS_IND   (WS_CAT + CAT_SZ)           // int inds
#define IND_SZ   (BN*KK)
#define WS_SSEL  (WS_IND + IND_SZ)           // selected score values

// ---------------------------------------------------------------------------
// Kernel 0: transpose conv1 weights OIHW(co,ci,ky,kx) -> [br][ci][k][co]
// ---------------------------------------------------------------------------
__global__ void k_transpose_w1(const float* __restrict__ cw,
                               const float* __restrict__ rw,
                               const float* __restrict__ ww,
                               float* __restrict__ wt) {
    int idx = blockIdx.x * 256 + threadIdx.x;
    if (idx >= 3*64*9*64) return;
    int co = idx & 63;
    int k  = (idx >> 6) % 9;
    int ci = (idx / 576) & 63;
    int br = idx / (576*64);
    const float* src = (br == 0) ? cw : (br == 1 ? rw : ww);
    wt[idx] = src[(co*64 + ci)*9 + k];
}

// ---------------------------------------------------------------------------
// Kernel 1: fused conv1(3x3)+bias+ReLU  ->  conv2(1x1)+bias+activation
// grid (y=128, b=16, branch=3), block 256
// branch 0: cls (80ch, sigmoid)  1: reg (2ch, sigmoid)  2: wh (2ch, exp)
// ---------------------------------------------------------------------------
__global__ __launch_bounds__(256) void k_conv_branch(
    const float* __restrict__ x, const float* __restrict__ wt1,
    const float* __restrict__ b1c, const float* __restrict__ b1r, const float* __restrict__ b1w,
    const float* __restrict__ w2c, const float* __restrict__ w2r, const float* __restrict__ w2w,
    const float* __restrict__ b2c, const float* __restrict__ b2r, const float* __restrict__ b2w,
    float* __restrict__ cls_o, float* __restrict__ reg_o, float* __restrict__ wh_o)
{
    __shared__ float lds[128*65];   // relu1 tile [px][65] (pad -> conflict-free)
    const int y    = blockIdx.x;
    const int b    = blockIdx.y;
    const int br   = blockIdx.z;
    const int tid  = threadIdx.x;
    const int lane = tid & 63;
    const int wave = tid >> 6;
    const int px      = ((wave >> 1) << 6) | lane;  // 0..127
    const int co_base = (wave & 1) << 5;            // 0 or 32

    const float* wtb = wt1 + br*36864;

    float acc[32];
    #pragma unroll
    for (int i = 0; i < 32; i++) acc[i] = 0.f;

    for (int ci = 0; ci < 64; ci++) {
        const float* xin = x + ((size_t)(b*64 + ci)*128 + y)*128;
        float iv[9];
        #pragma unroll
        for (int dy = 0; dy < 3; dy++) {
            int yy = y + dy - 1;
            bool yok = (yy >= 0) && (yy < 128);
            const float* rp = xin + (dy - 1)*128;
            #pragma unroll
            for (int dx = 0; dx < 3; dx++) {
                int xx = px + dx - 1;
                bool ok = yok && (xx >= 0) && (xx < 128);
                iv[dy*3 + dx] = ok ? rp[xx] : 0.f;
            }
        }
        // wave-uniform weight base -> scalar loads
        int wbase = __builtin_amdgcn_readfirstlane(ci*576 + co_base);
        #pragma unroll
        for (int k = 0; k < 9; k++) {
            const float4* wp = (const float4*)(wtb + wbase + k*64);
            float v = iv[k];
            #pragma unroll
            for (int q = 0; q < 8; q++) {
                float4 wv = wp[q];
                acc[q*4+0] += v*wv.x; acc[q*4+1] += v*wv.y;
                acc[q*4+2] += v*wv.z; acc[q*4+3] += v*wv.w;
            }
        }
    }

    const float* b1 = (br == 0) ? b1c : (br == 1 ? b1r : b1w);
    {
        int bb = __builtin_amdgcn_readfirstlane(co_base);
        #pragma unroll
        for (int q = 0; q < 32; q++) {
            float z = acc[q] + b1[bb + q];
            lds[px*65 + co_base + q] = (z > 0.f) ? z : 0.f;
        }
    }
    __syncthreads();

    const int px2  = tid & 127;
    const int half = tid >> 7;   // wave-uniform
    float rv[64];
    #pragma unroll
    for (int c = 0; c < 64; c++) rv[c] = lds[px2*65 + c];

    if (br == 0) {
        // cls: this thread does 40 output channels
        for (int j = 0; j < 40; j++) {
            int co2 = half*40 + j;
            int wof = __builtin_amdgcn_readfirstlane(co2*64);
            const float4* wp = (const float4*)(w2c + wof);
            float s = 0.f;
            #pragma unroll
            for (int q = 0; q < 16; q++) {
                float4 wv = wp[q];
                s += rv[q*4+0]*wv.x + rv[q*4+1]*wv.y + rv[q*4+2]*wv.z + rv[q*4+3]*wv.w;
            }
            s += b2c[__builtin_amdgcn_readfirstlane(co2)];
            float sg = 1.f / (1.f + expf(-s));
            cls_o[((size_t)(b*80 + co2)*128 + y)*128 + px2] = sg;
        }
    } else {
        int co2 = half;  // 0 or 1
        const float* w2 = (br == 1) ? w2r : w2w;
        const float* b2 = (br == 1) ? b2r : b2w;
        int wof = __builtin_amdgcn_readfirstlane(co2*64);
        const float4* wp = (const float4*)(w2 + wof);
        float s = 0.f;
        #pragma unroll
        for (int q = 0; q < 16; q++) {
            float4 wv = wp[q];
            s += rv[q*4+0]*wv.x + rv[q*4+1]*wv.y + rv[q*4+2]*wv.z + rv[q*4+3]*wv.w;
        }
        s += b2[__builtin_amdgcn_readfirstlane(co2)];
        float o = (br == 1) ? (1.f / (1.f + expf(-s))) : expf(s);
        float* outp = (br == 1) ? reg_o : wh_o;
        outp[((size_t)(b*2 + co2)*128 + y)*128 + px2] = o;
    }
}

// ---------------------------------------------------------------------------
// Kernel 2: 3x3 peak mask + max/argmax over classes
// grid (y=128, b=16), block 128
// ---------------------------------------------------------------------------
__global__ void k_peaks(const float* __restrict__ cls,
                        float* __restrict__ sc, int* __restrict__ cat) {
    const int y = blockIdx.x;
    const int b = blockIdx.y;
    const int xx0 = threadIdx.x;
    float best = -1.f;
    int bc = 0;
    for (int c = 0; c < 80; c++) {
        const float* pl = cls + (size_t)(b*80 + c)*HWSZ;
        float v = pl[y*128 + xx0];
        float m = v;
        #pragma unroll
        for (int dy = -1; dy <= 1; dy++) {
            int yy = y + dy;
            if (yy < 0 || yy > 127) continue;
            #pragma unroll
            for (int dx = -1; dx <= 1; dx++) {
                int xx = xx0 + dx;
                if (xx < 0 || xx > 127) continue;
                float u = pl[yy*128 + xx];
                m = (m > u) ? m : u;
            }
        }
        float masked = (v == m) ? v : 0.f;
        if (masked > best) { best = masked; bc = c; }  // strict > == first-max (jnp.argmax)
    }
    sc[b*HWSZ + y*128 + xx0]  = best;
    cat[b*HWSZ + y*128 + xx0] = bc;
}

// ---------------------------------------------------------------------------
// Kernel 3: per-batch top-100 (stable: ties -> smaller index, like lax.top_k)
// grid 16, block 256. Destroys sc.
// ---------------------------------------------------------------------------
__global__ void k_topk(float* __restrict__ sc,
                       int* __restrict__ inds, float* __restrict__ svals) {
    const int b = blockIdx.x;
    const int tid = threadIdx.x;
    __shared__ float wv_s[4];
    __shared__ int   wi_s[4];
    float* scb = sc + (size_t)b*HWSZ;
    for (int it = 0; it < KK; it++) {
        float bv = -10.f; int bi = 0;
        for (int i = tid; i < HWSZ; i += 256) {
            float v = scb[i];
            if (v > bv) { bv = v; bi = i; }   // ascending scan keeps smallest idx
        }
        #pragma unroll
        for (int off = 32; off >= 1; off >>= 1) {
            float ov = __shfl_down(bv, off);
            int   oi = __shfl_down(bi, off);
            if (ov > bv || (ov == bv && oi < bi)) { bv = ov; bi = oi; }
        }
        int wave = tid >> 6;
        if ((tid & 63) == 0) { wv_s[wave] = bv; wi_s[wave] = bi; }
        __syncthreads();
        if (tid == 0) {
            float fv = wv_s[0]; int fi = wi_s[0];
            for (int wq = 1; wq < 4; wq++) {
                float ov = wv_s[wq]; int oi = wi_s[wq];
                if (ov > fv || (ov == fv && oi < fi)) { fv = ov; fi = oi; }
            }
            inds[b*KK + it]  = fi;
            svals[b*KK + it] = fv;
            scb[fi] = -100.f;
        }
        __syncthreads();
    }
}

// ---------------------------------------------------------------------------
// Kernel 4: gather + box decode + sequential NMS + write all outputs
// grid 16, block 128
// out: boxes[16*100*4] | cats[1600] | scores[1600] | keep[1600]  (all fp32)
// ---------------------------------------------------------------------------
__global__ void k_nms(const int* __restrict__ inds, const float* __restrict__ svals,
                      const int* __restrict__ cats, const float* __restrict__ regp,
                      const float* __restrict__ whp, float* __restrict__ out) {
    const int b = blockIdx.x;
    const int j = threadIdx.x;
    __shared__ float X1[KK], Y1[KK], X2[KK], Y2[KK], AR[KK];
    __shared__ int keep[KK];
    if (j < KK) {
        int ind = inds[b*KK + j];
        float scv = svals[b*KK + j];
        const float* rb = regp + (size_t)b*2*HWSZ;
        const float* wb = whp  + (size_t)b*2*HWSZ;
        float r0 = rb[ind], r1 = rb[HWSZ + ind];
        float w0 = wb[ind], w1 = wb[HWSZ + ind];
        float ctx = (float)(ind & 127) + r0;
        float cty = (float)(ind >> 7) + r1;
        float x1 = (ctx - w0*0.5f)*4.f, y1 = (cty - w1*0.5f)*4.f;
        float x2 = (ctx + w0*0.5f)*4.f, y2 = (cty + w1*0.5f)*4.f;
        size_t bo = ((size_t)b*KK + j)*4;
        out[bo+0] = x1; out[bo+1] = y1; out[bo+2] = x2; out[bo+3] = y2;
        out[BN*KK*4 + b*KK + j]            = (float)cats[(size_t)b*HWSZ + ind];
        out[BN*KK*4 + BN*KK + b*KK + j]    = scv;
        X1[j] = x1; Y1[j] = y1; X2[j] = x2; Y2[j] = y2;
        AR[j] = (x2 - x1)*(y2 - y1);
        keep[j] = (scv > 0.2f) ? 1 : 0;
    }
    __syncthreads();
    for (int i = 0; i < KK; i++) {
        if (j < KK && j > i && keep[i] && keep[j]) {
            float iw = fminf(X2[i], X2[j]) - fmaxf(X1[i], X1[j]); iw = iw > 0.f ? iw : 0.f;
            float ih = fminf(Y2[i], Y2[j]) - fmaxf(Y1[i], Y1[j]); ih = ih > 0.f ? ih : 0.f;
            float inter = iw*ih;
            float iou = inter / (AR[i] + AR[j] - inter + 1e-9f);
            if (iou > 0.5f) keep[j] = 0;
        }
        __syncthreads();
    }
    if (j < KK) out[BN*KK*4 + 2*BN*KK + b*KK + j] = keep[j] ? 1.f : 0.f;
}

// ---------------------------------------------------------------------------
extern "C" void kernel_launch(void* const* d_in, const int* in_sizes, int n_in,
                              void* d_out, int out_size, void* d_ws, size_t ws_size,
                              hipStream_t stream) {
    const float* x      = (const float*)d_in[0];
    const float* cls_w1 = (const float*)d_in[1];
    const float* cls_b1 = (const float*)d_in[2];
    const float* cls_w2 = (const float*)d_in[3];
    const float* cls_b2 = (const float*)d_in[4];
    const float* reg_w1 = (const float*)d_in[5];
    const float* reg_b1 = (const float*)d_in[6];
    const float* reg_w2 = (const float*)d_in[7];
    const float* reg_b2 = (const float*)d_in[8];
    const float* wh_w1  = (const float*)d_in[9];
    const float* wh_b1  = (const float*)d_in[10];
    const float* wh_w2  = (const float*)d_in[11];
    const float* wh_b2  = (const float*)d_in[12];

    float* ws   = (float*)d_ws;
    float* wt1  = ws + WS_WT1;
    float* clsb = ws + WS_CLS;
    float* regb = ws + WS_REG;
    float* whb  = ws + WS_WH;
    float* scw  = ws + WS_SC;
    int*   cat  = (int*)(ws + WS_CAT);
    int*   inds = (int*)(ws + WS_IND);
    float* ssel = ws + WS_SSEL;
    float* out  = (float*)d_out;

    k_transpose_w1<<<(WT1_SZ + 255)/256, 256, 0, stream>>>(cls_w1, reg_w1, wh_w1, wt1);
    k_conv_branch<<<dim3(128, 16, 3), 256, 0, stream>>>(
        x, wt1, cls_b1, reg_b1, wh_b1, cls_w2, reg_w2, wh_w2,
        cls_b2, reg_b2, wh_b2, clsb, regb, whb);
    k_peaks<<<dim3(128, 16), 128, 0, stream>>>(clsb, scw, cat);
    k_topk<<<16, 256, 0, stream>>>(scw, inds, ssel);
    k_nms<<<16, 128, 0, stream>>>(inds, ssel, cat, regb, whb, out);
}

// Round 2
// 1643.811 us; speedup vs baseline: 1.1530x; 1.1530x over previous
//
#include <hip/hip_runtime.h>
#include <math.h>

// Problem constants
#define BN 16
#define CIN 64
#define HH 128
#define WW 128
#define HWSZ (HH*WW)          // 16384
#define NC 80
#define KK 100

// Workspace layout (in floats)
#define WS_WT1   0
#define WT1_SZ   (3*64*9*64)                 // 110592
#define WS_CLS   (WS_WT1 + WT1_SZ)
#define CLS_SZ   (BN*NC*HWSZ)                // 20,971,520
#define WS_REG   (WS_CLS + CLS_SZ)
#define REG_SZ   (BN*2*HWSZ)
#define WS_WH    (WS_REG + REG_SZ)
#define WH_SZ    (BN*2*HWSZ)
#define WS_SC    (WS_WH + WH_SZ)             // scores_all (destroyed by k_select)
#define SC_SZ    (BN*HWSZ)
#define WS_CAT   (WS_SC + SC_SZ)             // int cats_all
#define CAT_SZ   (BN*HWSZ)

// ---------------------------------------------------------------------------
// Kernel 0: transpose conv1 weights OIHW(co,ci,ky,kx) -> [br][ci][k][co]
// ---------------------------------------------------------------------------
__global__ void k_transpose_w1(const float* __restrict__ cw,
                               const float* __restrict__ rw,
                               const float* __restrict__ ww,
                               float* __restrict__ wt) {
    int idx = blockIdx.x * 256 + threadIdx.x;
    if (idx >= 3*64*9*64) return;
    int co = idx & 63;
    int k  = (idx >> 6) % 9;
    int ci = (idx / 576) & 63;
    int br = idx / (576*64);
    const float* src = (br == 0) ? cw : (br == 1 ? rw : ww);
    wt[idx] = src[(co*64 + ci)*9 + k];
}

// ---------------------------------------------------------------------------
// Kernel 1: fused conv1(3x3)+bias+ReLU  ->  conv2(1x1)+bias+activation
// grid (y=128, b=16, branch=3), block 256
// LDS: 128 px x 64 ch, XOR-swizzled on ch bits [4:2] -> exactly 32 KB
//      => 5 blocks/CU (160 KB), 20 waves/CU
// ---------------------------------------------------------------------------
__global__ __launch_bounds__(256, 5) void k_conv_branch(
    const float* __restrict__ x, const float* __restrict__ wt1,
    const float* __restrict__ b1c, const float* __restrict__ b1r, const float* __restrict__ b1w,
    const float* __restrict__ w2c, const float* __restrict__ w2r, const float* __restrict__ w2w,
    const float* __restrict__ b2c, const float* __restrict__ b2r, const float* __restrict__ b2w,
    float* __restrict__ cls_o, float* __restrict__ reg_o, float* __restrict__ wh_o)
{
    __shared__ float lds[128*64];   // [px][ch^sw] swizzled
    const int y    = blockIdx.x;
    const int b    = blockIdx.y;
    const int br   = blockIdx.z;
    const int tid  = threadIdx.x;
    const int lane = tid & 63;
    const int wave = tid >> 6;
    const int px      = ((wave >> 1) << 6) | lane;  // 0..127
    const int co_base = (wave & 1) << 5;            // 0 or 32

    const float* wtb = wt1 + br*36864;

    float acc[32];
    #pragma unroll
    for (int i = 0; i < 32; i++) acc[i] = 0.f;

    #pragma unroll 2
    for (int ci = 0; ci < 64; ci++) {
        const float* xin = x + ((size_t)(b*64 + ci)*128 + y)*128;
        float iv[9];
        #pragma unroll
        for (int dy = 0; dy < 3; dy++) {
            int yy = y + dy - 1;
            bool yok = (yy >= 0) && (yy < 128);
            const float* rp = xin + (dy - 1)*128;
            #pragma unroll
            for (int dx = 0; dx < 3; dx++) {
                int xx = px + dx - 1;
                bool ok = yok && (xx >= 0) && (xx < 128);
                iv[dy*3 + dx] = ok ? rp[xx] : 0.f;
            }
        }
        // wave-uniform weight base -> scalar loads
        int wbase = __builtin_amdgcn_readfirstlane(ci*576 + co_base);
        #pragma unroll
        for (int k = 0; k < 9; k++) {
            const float4* wp = (const float4*)(wtb + wbase + k*64);
            float v = iv[k];
            #pragma unroll
            for (int q = 0; q < 8; q++) {
                float4 wv = wp[q];
                acc[q*4+0] += v*wv.x; acc[q*4+1] += v*wv.y;
                acc[q*4+2] += v*wv.z; acc[q*4+3] += v*wv.w;
            }
        }
    }

    const float* b1 = (br == 0) ? b1c : (br == 1 ? b1r : b1w);
    {
        const int swp = px & 28;                    // XOR swizzle bits [4:2]
        #pragma unroll
        for (int q4 = 0; q4 < 32; q4 += 4) {
            int c = co_base + q4;
            float4 t4;
            t4.x = fmaxf(acc[q4+0] + b1[c+0], 0.f);
            t4.y = fmaxf(acc[q4+1] + b1[c+1], 0.f);
            t4.z = fmaxf(acc[q4+2] + b1[c+2], 0.f);
            t4.w = fmaxf(acc[q4+3] + b1[c+3], 0.f);
            *(float4*)&lds[px*64 + (c ^ swp)] = t4;
        }
    }
    __syncthreads();

    const int px2  = tid & 127;
    const int half = tid >> 7;   // wave-uniform
    const int sw2  = px2 & 28;
    float rv[64];
    #pragma unroll
    for (int c4 = 0; c4 < 64; c4 += 4) {
        float4 vv = *(const float4*)&lds[px2*64 + (c4 ^ sw2)];
        rv[c4+0] = vv.x; rv[c4+1] = vv.y; rv[c4+2] = vv.z; rv[c4+3] = vv.w;
    }

    if (br == 0) {
        // cls: this thread does 40 output channels
        #pragma unroll 4
        for (int j = 0; j < 40; j++) {
            int co2 = half*40 + j;
            int wof = __builtin_amdgcn_readfirstlane(co2*64);
            const float4* wp = (const float4*)(w2c + wof);
            float s = 0.f;
            #pragma unroll
            for (int q = 0; q < 16; q++) {
                float4 wv = wp[q];
                s += rv[q*4+0]*wv.x + rv[q*4+1]*wv.y + rv[q*4+2]*wv.z + rv[q*4+3]*wv.w;
            }
            s += b2c[__builtin_amdgcn_readfirstlane(co2)];
            float sg = 1.f / (1.f + expf(-s));
            cls_o[((size_t)(b*80 + co2)*128 + y)*128 + px2] = sg;
        }
    } else {
        int co2 = half;  // 0 or 1
        const float* w2 = (br == 1) ? w2r : w2w;
        const float* b2 = (br == 1) ? b2r : b2w;
        int wof = __builtin_amdgcn_readfirstlane(co2*64);
        const float4* wp = (const float4*)(w2 + wof);
        float s = 0.f;
        #pragma unroll
        for (int q = 0; q < 16; q++) {
            float4 wv = wp[q];
            s += rv[q*4+0]*wv.x + rv[q*4+1]*wv.y + rv[q*4+2]*wv.z + rv[q*4+3]*wv.w;
        }
        s += b2[__builtin_amdgcn_readfirstlane(co2)];
        float o = (br == 1) ? (1.f / (1.f + expf(-s))) : expf(s);
        float* outp = (br == 1) ? reg_o : wh_o;
        outp[((size_t)(b*2 + co2)*128 + y)*128 + px2] = o;
    }
}

// ---------------------------------------------------------------------------
// Kernel 2: 3x3 peak mask + max/argmax over classes
// grid (y=128, b=16), block 128. Vertical max in regs, horizontal via LDS
// (double-buffered -> 1 barrier per class). 3 global loads/class vs 9.
// ---------------------------------------------------------------------------
__global__ void k_peaks(const float* __restrict__ cls,
                        float* __restrict__ sc, int* __restrict__ cat) {
    __shared__ float vmb[2][130];
    const int y  = blockIdx.x;
    const int b  = blockIdx.y;
    const int px = threadIdx.x;
    float best = -1.f;
    int bc = 0;
    for (int c = 0; c < 80; c++) {
        const float* pl = cls + (size_t)(b*80 + c)*HWSZ + y*128;
        float v  = pl[px];
        float t  = (y > 0)   ? pl[px - 128] : -1e30f;
        float bo = (y < 127) ? pl[px + 128] : -1e30f;
        float m3 = fmaxf(v, fmaxf(t, bo));
        float* buf = vmb[c & 1];
        buf[px + 1] = m3;
        if (px == 0)   buf[0]   = -1e30f;
        if (px == 127) buf[129] = -1e30f;
        __syncthreads();
        float m = fmaxf(buf[px], fmaxf(buf[px + 1], buf[px + 2]));
        float masked = (v == m) ? v : 0.f;
        if (masked > best) { best = masked; bc = c; }  // strict > == first-max
        // no 2nd barrier: buffer (c&1) is only rewritten at c+2, after the
        // c+1 barrier which all threads must pass having finished this read.
    }
    sc[b*HWSZ + y*128 + px]  = best;
    cat[b*HWSZ + y*128 + px] = bc;
}

// ---------------------------------------------------------------------------
// Kernel 3: fused per-batch top-100 + box decode + NMS + all outputs.
// grid 16, block 256. Destroys sc.
// Phase A: 64 chunk-maxima (chunk=256 elems), exact first-max index.
// Phase B: wave0 only -- 100x (64-lane argmax + 256-elem chunk rescan).
// Phase C: threads<100 decode boxes, write boxes/cats/scores.
// Phase D: wave0 NMS via shfl (no barriers), write keep.
// ---------------------------------------------------------------------------
__global__ void k_select(float* __restrict__ sc, const int* __restrict__ cats,
                         const float* __restrict__ regp, const float* __restrict__ whp,
                         float* __restrict__ out) {
    const int b   = blockIdx.x;
    const int tid = threadIdx.x;
    float* scb = sc + (size_t)b*HWSZ;

    __shared__ float cmax[64];
    __shared__ int   cidx[64];
    __shared__ int   s_inds[KK];
    __shared__ float s_vals[KK];
    __shared__ float X1[KK], Y1[KK], X2[KK], Y2[KK], AR[KK];

    // ---- Phase A: per-chunk max (value desc, first index) ----
    {
        int c = tid >> 2, q = tid & 3;
        int base = c*256 + q*64;
        float bv = -1e30f; int bi = base;
        for (int e = 0; e < 64; e++) {
            float v = scb[base + e];
            if (v > bv) { bv = v; bi = base + e; }   // ascending: keeps first
        }
        #pragma unroll
        for (int off = 1; off <= 2; off <<= 1) {
            float ov = __shfl_xor(bv, off);
            int   oi = __shfl_xor(bi, off);
            if (ov > bv || (ov == bv && oi < bi)) { bv = ov; bi = oi; }
        }
        if (q == 0) { cmax[c] = bv; cidx[c] = bi; }
    }
    __syncthreads();

    // ---- Phase B: 100 selections, wave 0 only ----
    if (tid < 64) {
        const int l = tid;
        float v = cmax[l]; int ix = cidx[l];
        for (int it = 0; it < KK; it++) {
            float rv = v; int ri = ix;
            #pragma unroll
            for (int off = 32; off >= 1; off >>= 1) {
                float ov = __shfl_down(rv, off);
                int   oi = __shfl_down(ri, off);
                if (ov > rv || (ov == rv && oi < ri)) { rv = ov; ri = oi; }
            }
            float fv = __shfl(rv, 0);
            int   fi = __shfl(ri, 0);
            if (l == 0) { s_inds[it] = fi; s_vals[it] = fv; scb[fi] = -1e30f; }
            int wc = fi >> 8;                 // winning chunk
            // rescan chunk wc (256 elems, 4/lane contiguous)
            int eb = wc*256 + l*4;
            float nv = -1e30f; int ni = eb;
            #pragma unroll
            for (int r = 0; r < 4; r++) {
                float u = scb[eb + r];
                if (u > nv) { nv = u; ni = eb + r; }
            }
            #pragma unroll
            for (int off = 32; off >= 1; off >>= 1) {
                float ov = __shfl_down(nv, off);
                int   oi = __shfl_down(ni, off);
                if (ov > nv || (ov == nv && oi < ni)) { nv = ov; ni = oi; }
            }
            float cv = __shfl(nv, 0);
            int   ci2 = __shfl(ni, 0);
            if (l == wc) { v = cv; ix = ci2; }
        }
    }
    __syncthreads();

    // ---- Phase C: decode boxes for the 100 selections ----
    if (tid < KK) {
        int ind   = s_inds[tid];
        float scv = s_vals[tid];
        const float* rb = regp + (size_t)b*2*HWSZ;
        const float* wb = whp  + (size_t)b*2*HWSZ;
        float r0 = rb[ind], r1 = rb[HWSZ + ind];
        float w0 = wb[ind], w1 = wb[HWSZ + ind];
        float ctx = (float)(ind & 127) + r0;
        float cty = (float)(ind >> 7) + r1;
        float x1 = (ctx - w0*0.5f)*4.f, y1 = (cty - w1*0.5f)*4.f;
        float x2 = (ctx + w0*0.5f)*4.f, y2 = (cty + w1*0.5f)*4.f;
        size_t bo = ((size_t)b*KK + tid)*4;
        out[bo+0] = x1; out[bo+1] = y1; out[bo+2] = x2; out[bo+3] = y2;
        out[BN*KK*4 + b*KK + tid]         = (float)cats[(size_t)b*HWSZ + ind];
        out[BN*KK*4 + BN*KK + b*KK + tid] = scv;
        X1[tid] = x1; Y1[tid] = y1; X2[tid] = x2; Y2[tid] = y2;
        AR[tid] = (x2 - x1)*(y2 - y1);
    }
    __syncthreads();

    // ---- Phase D: NMS in wave 0, no barriers ----
    if (tid < 64) {
        const int l = tid;
        float x1a = X1[l], y1a = Y1[l], x2a = X2[l], y2a = Y2[l], ara = AR[l];
        int   ka  = (s_vals[l] > 0.2f) ? 1 : 0;
        float x1b = 0, y1b = 0, x2b = 0, y2b = 0, arb = 0;
        int   kb  = 0;
        if (l < KK - 64) {
            x1b = X1[64+l]; y1b = Y1[64+l]; x2b = X2[64+l]; y2b = Y2[64+l];
            arb = AR[64+l];
            kb  = (s_vals[64+l] > 0.2f) ? 1 : 0;
        }
        for (int i = 0; i < KK; i++) {
            float jx1, jy1, jx2, jy2, jar; int jk;
            if (i < 64) {
                jx1 = __shfl(x1a, i); jy1 = __shfl(y1a, i);
                jx2 = __shfl(x2a, i); jy2 = __shfl(y2a, i);
                jar = __shfl(ara, i); jk  = __shfl(ka,  i);
            } else {
                int li = i - 64;
                jx1 = __shfl(x1b, li); jy1 = __shfl(y1b, li);
                jx2 = __shfl(x2b, li); jy2 = __shfl(y2b, li);
                jar = __shfl(arb, li); jk  = __shfl(kb,  li);
            }
            if (jk) {
                if (ka && l > i) {
                    float iw = fminf(jx2, x2a) - fmaxf(jx1, x1a); iw = iw > 0.f ? iw : 0.f;
                    float ih = fminf(jy2, y2a) - fmaxf(jy1, y1a); ih = ih > 0.f ? ih : 0.f;
                    float inter = iw*ih;
                    float iou = inter / (jar + ara - inter + 1e-9f);
                    if (iou > 0.5f) ka = 0;
                }
                if (kb && (64 + l) > i) {
                    float iw = fminf(jx2, x2b) - fmaxf(jx1, x1b); iw = iw > 0.f ? iw : 0.f;
                    float ih = fminf(jy2, y2b) - fmaxf(jy1, y1b); ih = ih > 0.f ? ih : 0.f;
                    float inter = iw*ih;
                    float iou = inter / (jar + arb - inter + 1e-9f);
                    if (iou > 0.5f) kb = 0;
                }
            }
        }
        int koff = BN*KK*4 + 2*BN*KK;
        out[koff + b*KK + l] = ka ? 1.f : 0.f;
        if (l < KK - 64) out[koff + b*KK + 64 + l] = kb ? 1.f : 0.f;
    }
}

// ---------------------------------------------------------------------------
extern "C" void kernel_launch(void* const* d_in, const int* in_sizes, int n_in,
                              void* d_out, int out_size, void* d_ws, size_t ws_size,
                              hipStream_t stream) {
    const float* x      = (const float*)d_in[0];
    const float* cls_w1 = (const float*)d_in[1];
    const float* cls_b1 = (const float*)d_in[2];
    const float* cls_w2 = (const float*)d_in[3];
    const float* cls_b2 = (const float*)d_in[4];
    const float* reg_w1 = (const float*)d_in[5];
    const float* reg_b1 = (const float*)d_in[6];
    const float* reg_w2 = (const float*)d_in[7];
    const float* reg_b2 = (const float*)d_in[8];
    const float* wh_w1  = (const float*)d_in[9];
    const float* wh_b1  = (const float*)d_in[10];
    const float* wh_w2  = (const float*)d_in[11];
    const float* wh_b2  = (const float*)d_in[12];

    float* ws   = (float*)d_ws;
    float* wt1  = ws + WS_WT1;
    float* clsb = ws + WS_CLS;
    float* regb = ws + WS_REG;
    float* whb  = ws + WS_WH;
    float* scw  = ws + WS_SC;
    int*   cat  = (int*)(ws + WS_CAT);
    float* out  = (float*)d_out;

    k_transpose_w1<<<(WT1_SZ + 255)/256, 256, 0, stream>>>(cls_w1, reg_w1, wh_w1, wt1);
    k_conv_branch<<<dim3(128, 16, 3), 256, 0, stream>>>(
        x, wt1, cls_b1, reg_b1, wh_b1, cls_w2, reg_w2, wh_w2,
        cls_b2, reg_b2, wh_b2, clsb, regb, whb);
    k_peaks<<<dim3(128, 16), 128, 0, stream>>>(clsb, scw, cat);
    k_select<<<16, 256, 0, stream>>>(scw, cat, regb, whb, out);
}

// Round 3
// 1081.830 us; speedup vs baseline: 1.7519x; 1.5195x over previous
//
#include <hip/hip_runtime.h>
#include <math.h>

// Problem constants
#define BN 16
#define CIN 64
#define HH 128
#define WW 128
#define HWSZ (HH*WW)          // 16384
#define NC 80
#define KK 100

// Workspace layout (in floats)
#define WS_WT1   0
#define WT1_SZ   (3*64*9*64)                 // 110592
#define WS_CLS   (WS_WT1 + WT1_SZ)
#define CLS_SZ   (BN*NC*HWSZ)                // 20,971,520
#define WS_REG   (WS_CLS + CLS_SZ)
#define REG_SZ   (BN*2*HWSZ)
#define WS_WH    (WS_REG + REG_SZ)
#define WH_SZ    (BN*2*HWSZ)
#define WS_SC    (WS_WH + WH_SZ)             // scores_all (destroyed by k_select)
#define SC_SZ    (BN*HWSZ)
#define WS_CAT   (WS_SC + SC_SZ)             // int cats_all
#define CAT_SZ   (BN*HWSZ)

// ---------------------------------------------------------------------------
// Kernel 0: transpose conv1 weights OIHW(co,ci,ky,kx) -> [br][ci][k][co]
// ---------------------------------------------------------------------------
__global__ void k_transpose_w1(const float* __restrict__ cw,
                               const float* __restrict__ rw,
                               const float* __restrict__ ww,
                               float* __restrict__ wt) {
    int idx = blockIdx.x * 256 + threadIdx.x;
    if (idx >= 3*64*9*64) return;
    int co = idx & 63;
    int k  = (idx >> 6) % 9;
    int ci = (idx / 576) & 63;
    int br = idx / (576*64);
    const float* src = (br == 0) ? cw : (br == 1 ? rw : ww);
    wt[idx] = src[(co*64 + ci)*9 + k];
}

// ---------------------------------------------------------------------------
// Kernel 1: fused conv1(3x3)+bias+ReLU -> conv2(1x1)+bias+activation.
// grid (y=128, b=16, branch=3), block 128 (one px per thread).
// Each thread accumulates ALL 64 conv1 channels for its pixel:
//  - per ci: 9 input loads feed 576 FMAs (64:1), weights are wave-uniform
//    (readfirstlane'd offsets -> s_load, SGPR operand in v_fmac)
//  - conv2 runs fully in registers: NO LDS, NO barrier -> VGPR-bound occupancy
// NOTE: no min-waves launch bound — round-2 showed forcing occupancy makes the
// allocator insert ~1.8x copy traffic (VGPR 60->48, conv 890->1470 us).
// ---------------------------------------------------------------------------
__global__ __launch_bounds__(128) void k_conv_branch(
    const float* __restrict__ x, const float* __restrict__ wt1,
    const float* __restrict__ b1c, const float* __restrict__ b1r, const float* __restrict__ b1w,
    const float* __restrict__ w2c, const float* __restrict__ w2r, const float* __restrict__ w2w,
    const float* __restrict__ b2c, const float* __restrict__ b2r, const float* __restrict__ b2w,
    float* __restrict__ cls_o, float* __restrict__ reg_o, float* __restrict__ wh_o)
{
    const int y  = blockIdx.x;
    const int b  = blockIdx.y;
    const int br = blockIdx.z;
    const int px = threadIdx.x;       // 0..127

    const float* wtb = wt1 + __builtin_amdgcn_readfirstlane(br*36864);

    float acc[64];
    #pragma unroll
    for (int i = 0; i < 64; i++) acc[i] = 0.f;

    const bool ytop = (y > 0);        // block-uniform
    const bool ybot = (y < 127);      // block-uniform
    const bool xl   = (px > 0);       // per-lane (edge lanes only)
    const bool xr   = (px < 127);

    for (int ci = 0; ci < 64; ci++) {
        const float* rp = x + ((size_t)(b*64 + ci)*128 + y)*128 + px;
        float iv[9];
        iv[0] = (ytop && xl) ? rp[-129] : 0.f;
        iv[1] =  ytop        ? rp[-128] : 0.f;
        iv[2] = (ytop && xr) ? rp[-127] : 0.f;
        iv[3] =  xl          ? rp[-1]   : 0.f;
        iv[4] =                rp[0];
        iv[5] =  xr          ? rp[1]    : 0.f;
        iv[6] = (ybot && xl) ? rp[127]  : 0.f;
        iv[7] =  ybot        ? rp[128]  : 0.f;
        iv[8] = (ybot && xr) ? rp[129]  : 0.f;

        const float* wci = wtb + __builtin_amdgcn_readfirstlane(ci*576);
        #pragma unroll
        for (int k = 0; k < 9; k++) {
            float v = iv[k];
            const float* wk = wci + k*64;   // uniform -> s_load
            #pragma unroll
            for (int c = 0; c < 64; c++)
                acc[c] += v * wk[c];
        }
    }

    // bias + ReLU (b1 uniform -> scalar loads)
    const float* b1 = (br == 0) ? b1c : (br == 1 ? b1r : b1w);
    #pragma unroll
    for (int c = 0; c < 64; c++)
        acc[c] = fmaxf(acc[c] + b1[c], 0.f);

    if (br == 0) {
        float* outrow = cls_o + (size_t)b*80*HWSZ + y*128 + px;
        for (int co2 = 0; co2 < 80; co2++) {
            const float* w2row = w2c + __builtin_amdgcn_readfirstlane(co2*64);
            float s0 = 0.f, s1 = 0.f, s2 = 0.f, s3 = 0.f;
            #pragma unroll
            for (int c = 0; c < 64; c += 4) {
                s0 += acc[c+0]*w2row[c+0];
                s1 += acc[c+1]*w2row[c+1];
                s2 += acc[c+2]*w2row[c+2];
                s3 += acc[c+3]*w2row[c+3];
            }
            float s = ((s0+s1)+(s2+s3)) + b2c[co2];
            outrow[(size_t)co2*HWSZ] = 1.f/(1.f + expf(-s));
        }
    } else {
        const float* w2  = (br == 1) ? w2r : w2w;
        const float* b2  = (br == 1) ? b2r : b2w;
        float* outp      = (br == 1) ? reg_o : wh_o;
        #pragma unroll
        for (int co2 = 0; co2 < 2; co2++) {
            const float* w2row = w2 + co2*64;
            float s0 = 0.f, s1 = 0.f, s2 = 0.f, s3 = 0.f;
            #pragma unroll
            for (int c = 0; c < 64; c += 4) {
                s0 += acc[c+0]*w2row[c+0];
                s1 += acc[c+1]*w2row[c+1];
                s2 += acc[c+2]*w2row[c+2];
                s3 += acc[c+3]*w2row[c+3];
            }
            float s = ((s0+s1)+(s2+s3)) + b2[co2];
            float o = (br == 1) ? (1.f/(1.f + expf(-s))) : expf(s);
            outp[((size_t)(b*2 + co2))*HWSZ + y*128 + px] = o;
        }
    }
}

// ---------------------------------------------------------------------------
// Kernel 2: 3x3 peak mask + max/argmax over classes
// grid (y=128, b=16), block 128. Vertical max in regs, horizontal via LDS
// (double-buffered -> 1 barrier per class). 3 global loads/class vs 9.
// ---------------------------------------------------------------------------
__global__ void k_peaks(const float* __restrict__ cls,
                        float* __restrict__ sc, int* __restrict__ cat) {
    __shared__ float vmb[2][130];
    const int y  = blockIdx.x;
    const int b  = blockIdx.y;
    const int px = threadIdx.x;
    float best = -1.f;
    int bc = 0;
    for (int c = 0; c < 80; c++) {
        const float* pl = cls + (size_t)(b*80 + c)*HWSZ + y*128;
        float v  = pl[px];
        float t  = (y > 0)   ? pl[px - 128] : -1e30f;
        float bo = (y < 127) ? pl[px + 128] : -1e30f;
        float m3 = fmaxf(v, fmaxf(t, bo));
        float* buf = vmb[c & 1];
        buf[px + 1] = m3;
        if (px == 0)   buf[0]   = -1e30f;
        if (px == 127) buf[129] = -1e30f;
        __syncthreads();
        float m = fmaxf(buf[px], fmaxf(buf[px + 1], buf[px + 2]));
        float masked = (v == m) ? v : 0.f;
        if (masked > best) { best = masked; bc = c; }  // strict > == first-max
        // no 2nd barrier: buffer (c&1) is only rewritten at c+2, after the
        // c+1 barrier which all threads must pass having finished this read.
    }
    sc[b*HWSZ + y*128 + px]  = best;
    cat[b*HWSZ + y*128 + px] = bc;
}

// ---------------------------------------------------------------------------
// Kernel 3: fused per-batch top-100 + box decode + NMS + all outputs.
// grid 16, block 256. Destroys sc.
// ---------------------------------------------------------------------------
__global__ void k_select(float* __restrict__ sc, const int* __restrict__ cats,
                         const float* __restrict__ regp, const float* __restrict__ whp,
                         float* __restrict__ out) {
    const int b   = blockIdx.x;
    const int tid = threadIdx.x;
    float* scb = sc + (size_t)b*HWSZ;

    __shared__ float cmax[64];
    __shared__ int   cidx[64];
    __shared__ int   s_inds[KK];
    __shared__ float s_vals[KK];
    __shared__ float X1[KK], Y1[KK], X2[KK], Y2[KK], AR[KK];

    // ---- Phase A: per-chunk max (value desc, first index) ----
    {
        int c = tid >> 2, q = tid & 3;
        int base = c*256 + q*64;
        float bv = -1e30f; int bi = base;
        for (int e = 0; e < 64; e++) {
            float v = scb[base + e];
            if (v > bv) { bv = v; bi = base + e; }   // ascending: keeps first
        }
        #pragma unroll
        for (int off = 1; off <= 2; off <<= 1) {
            float ov = __shfl_xor(bv, off);
            int   oi = __shfl_xor(bi, off);
            if (ov > bv || (ov == bv && oi < bi)) { bv = ov; bi = oi; }
        }
        if (q == 0) { cmax[c] = bv; cidx[c] = bi; }
    }
    __syncthreads();

    // ---- Phase B: 100 selections, wave 0 only ----
    if (tid < 64) {
        const int l = tid;
        float v = cmax[l]; int ix = cidx[l];
        for (int it = 0; it < KK; it++) {
            float rv = v; int ri = ix;
            #pragma unroll
            for (int off = 32; off >= 1; off >>= 1) {
                float ov = __shfl_down(rv, off);
                int   oi = __shfl_down(ri, off);
                if (ov > rv || (ov == rv && oi < ri)) { rv = ov; ri = oi; }
            }
            float fv = __shfl(rv, 0);
            int   fi = __shfl(ri, 0);
            if (l == 0) { s_inds[it] = fi; s_vals[it] = fv; scb[fi] = -1e30f; }
            int wc = fi >> 8;                 // winning chunk
            int eb = wc*256 + l*4;
            float nv = -1e30f; int ni = eb;
            #pragma unroll
            for (int r = 0; r < 4; r++) {
                float u = scb[eb + r];
                if (u > nv) { nv = u; ni = eb + r; }
            }
            #pragma unroll
            for (int off = 32; off >= 1; off >>= 1) {
                float ov = __shfl_down(nv, off);
                int   oi = __shfl_down(ni, off);
                if (ov > nv || (ov == nv && oi < ni)) { nv = ov; ni = oi; }
            }
            float cv = __shfl(nv, 0);
            int   ci2 = __shfl(ni, 0);
            if (l == wc) { v = cv; ix = ci2; }
        }
    }
    __syncthreads();

    // ---- Phase C: decode boxes for the 100 selections ----
    if (tid < KK) {
        int ind   = s_inds[tid];
        float scv = s_vals[tid];
        const float* rb = regp + (size_t)b*2*HWSZ;
        const float* wb = whp  + (size_t)b*2*HWSZ;
        float r0 = rb[ind], r1 = rb[HWSZ + ind];
        float w0 = wb[ind], w1 = wb[HWSZ + ind];
        float ctx = (float)(ind & 127) + r0;
        float cty = (float)(ind >> 7) + r1;
        float x1 = (ctx - w0*0.5f)*4.f, y1 = (cty - w1*0.5f)*4.f;
        float x2 = (ctx + w0*0.5f)*4.f, y2 = (cty + w1*0.5f)*4.f;
        size_t bo = ((size_t)b*KK + tid)*4;
        out[bo+0] = x1; out[bo+1] = y1; out[bo+2] = x2; out[bo+3] = y2;
        out[BN*KK*4 + b*KK + tid]         = (float)cats[(size_t)b*HWSZ + ind];
        out[BN*KK*4 + BN*KK + b*KK + tid] = scv;
        X1[tid] = x1; Y1[tid] = y1; X2[tid] = x2; Y2[tid] = y2;
        AR[tid] = (x2 - x1)*(y2 - y1);
    }
    __syncthreads();

    // ---- Phase D: NMS in wave 0, no barriers ----
    if (tid < 64) {
        const int l = tid;
        float x1a = X1[l], y1a = Y1[l], x2a = X2[l], y2a = Y2[l], ara = AR[l];
        int   ka  = (s_vals[l] > 0.2f) ? 1 : 0;
        float x1b = 0, y1b = 0, x2b = 0, y2b = 0, arb = 0;
        int   kb  = 0;
        if (l < KK - 64) {
            x1b = X1[64+l]; y1b = Y1[64+l]; x2b = X2[64+l]; y2b = Y2[64+l];
            arb = AR[64+l];
            kb  = (s_vals[64+l] > 0.2f) ? 1 : 0;
        }
        for (int i = 0; i < KK; i++) {
            float jx1, jy1, jx2, jy2, jar; int jk;
            if (i < 64) {
                jx1 = __shfl(x1a, i); jy1 = __shfl(y1a, i);
                jx2 = __shfl(x2a, i); jy2 = __shfl(y2a, i);
                jar = __shfl(ara, i); jk  = __shfl(ka,  i);
            } else {
                int li = i - 64;
                jx1 = __shfl(x1b, li); jy1 = __shfl(y1b, li);
                jx2 = __shfl(x2b, li); jy2 = __shfl(y2b, li);
                jar = __shfl(arb, li); jk  = __shfl(kb,  li);
            }
            if (jk) {
                if (ka && l > i) {
                    float iw = fminf(jx2, x2a) - fmaxf(jx1, x1a); iw = iw > 0.f ? iw : 0.f;
                    float ih = fminf(jy2, y2a) - fmaxf(jy1, y1a); ih = ih > 0.f ? ih : 0.f;
                    float inter = iw*ih;
                    float iou = inter / (jar + ara - inter + 1e-9f);
                    if (iou > 0.5f) ka = 0;
                }
                if (kb && (64 + l) > i) {
                    float iw = fminf(jx2, x2b) - fmaxf(jx1, x1b); iw = iw > 0.f ? iw : 0.f;
                    float ih = fminf(jy2, y2b) - fmaxf(jy1, y1b); ih = ih > 0.f ? ih : 0.f;
                    float inter = iw*ih;
                    float iou = inter / (jar + arb - inter + 1e-9f);
                    if (iou > 0.5f) kb = 0;
                }
            }
        }
        int koff = BN*KK*4 + 2*BN*KK;
        out[koff + b*KK + l] = ka ? 1.f : 0.f;
        if (l < KK - 64) out[koff + b*KK + 64 + l] = kb ? 1.f : 0.f;
    }
}

// ---------------------------------------------------------------------------
extern "C" void kernel_launch(void* const* d_in, const int* in_sizes, int n_in,
                              void* d_out, int out_size, void* d_ws, size_t ws_size,
                              hipStream_t stream) {
    const float* x      = (const float*)d_in[0];
    const float* cls_w1 = (const float*)d_in[1];
    const float* cls_b1 = (const float*)d_in[2];
    const float* cls_w2 = (const float*)d_in[3];
    const float* cls_b2 = (const float*)d_in[4];
    const float* reg_w1 = (const float*)d_in[5];
    const float* reg_b1 = (const float*)d_in[6];
    const float* reg_w2 = (const float*)d_in[7];
    const float* reg_b2 = (const float*)d_in[8];
    const float* wh_w1  = (const float*)d_in[9];
    const float* wh_b1  = (const float*)d_in[10];
    const float* wh_w2  = (const float*)d_in[11];
    const float* wh_b2  = (const float*)d_in[12];

    float* ws   = (float*)d_ws;
    float* wt1  = ws + WS_WT1;
    float* clsb = ws + WS_CLS;
    float* regb = ws + WS_REG;
    float* whb  = ws + WS_WH;
    float* scw  = ws + WS_SC;
    int*   cat  = (int*)(ws + WS_CAT);
    float* out  = (float*)d_out;

    k_transpose_w1<<<(WT1_SZ + 255)/256, 256, 0, stream>>>(cls_w1, reg_w1, wh_w1, wt1);
    k_conv_branch<<<dim3(128, 16, 3), 128, 0, stream>>>(
        x, wt1, cls_b1, reg_b1, wh_b1, cls_w2, reg_w2, wh_w2,
        cls_b2, reg_b2, wh_b2, clsb, regb, whb);
    k_peaks<<<dim3(128, 16), 128, 0, stream>>>(clsb, scw, cat);
    k_select<<<16, 256, 0, stream>>>(scw, cat, regb, whb, out);
}

// Round 4
// 982.026 us; speedup vs baseline: 1.9300x; 1.1016x over previous
//
#include <hip/hip_runtime.h>
#include <math.h>

// Problem constants
#define BN 16
#define CIN 64
#define HH 128
#define WW 128
#define HWSZ (HH*WW)          // 16384
#define NC 80
#define KK 100

// Workspace layout (in floats)
#define WS_WT1   0
#define WT1_SZ   (3*64*9*64)                 // 110592
#define WS_CLS   (WS_WT1 + WT1_SZ)
#define CLS_SZ   (BN*NC*HWSZ)                // 20,971,520
#define WS_REG   (WS_CLS + CLS_SZ)
#define REG_SZ   (BN*2*HWSZ)
#define WS_WH    (WS_REG + REG_SZ)
#define WH_SZ    (BN*2*HWSZ)
#define WS_SC    (WS_WH + WH_SZ)             // scores_all (destroyed by k_select)
#define SC_SZ    (BN*HWSZ)
#define WS_CAT   (WS_SC + SC_SZ)             // int cats_all
#define CAT_SZ   (BN*HWSZ)

// ---------------------------------------------------------------------------
// Kernel 0: transpose conv1 weights OIHW(co,ci,ky,kx) -> [br][ci][k][co]
// ---------------------------------------------------------------------------
__global__ void k_transpose_w1(const float* __restrict__ cw,
                               const float* __restrict__ rw,
                               const float* __restrict__ ww,
                               float* __restrict__ wt) {
    int idx = blockIdx.x * 256 + threadIdx.x;
    if (idx >= 3*64*9*64) return;
    int co = idx & 63;
    int k  = (idx >> 6) % 9;
    int ci = (idx / 576) & 63;
    int br = idx / (576*64);
    const float* src = (br == 0) ? cw : (br == 1 ? rw : ww);
    wt[idx] = src[(co*64 + ci)*9 + k];
}

// ---------------------------------------------------------------------------
// Kernel 1: fused conv1(3x3)+bias+ReLU -> conv2(1x1)+bias+activation.
// grid (y-pair=64, b=16, branch=3), block 128 (one px, TWO rows per thread).
// Rationale (r3 post-mortem): with 1 row/thread each k-step's 64 uniform
// weight loads feed only 64 FMAs and the weight regs are reused every k ->
// per-k waitcnt stall, VALUBusy 55%. Two rows reuse the same weights for
// 128 FMAs (2x stall cover) and share input rows (12 loads / 2 px vs 18).
// FMA order per output unchanged -> bit-identical to r3 (absmax 0).
// No min-waves bound (r2 lesson: forcing occupancy bloats instruction count).
// ---------------------------------------------------------------------------
__global__ __launch_bounds__(128) void k_conv_branch(
    const float* __restrict__ x, const float* __restrict__ wt1,
    const float* __restrict__ b1c, const float* __restrict__ b1r, const float* __restrict__ b1w,
    const float* __restrict__ w2c, const float* __restrict__ w2r, const float* __restrict__ w2w,
    const float* __restrict__ b2c, const float* __restrict__ b2r, const float* __restrict__ b2w,
    float* __restrict__ cls_o, float* __restrict__ reg_o, float* __restrict__ wh_o)
{
    const int y0 = blockIdx.x * 2;    // output rows y0, y0+1
    const int b  = blockIdx.y;
    const int br = blockIdx.z;
    const int px = threadIdx.x;       // 0..127

    const float* wtb = wt1 + __builtin_amdgcn_readfirstlane(br*36864);

    float acc0[64], acc1[64];
    #pragma unroll
    for (int i = 0; i < 64; i++) { acc0[i] = 0.f; acc1[i] = 0.f; }

    const bool ytop = (y0 > 0);       // row y0-1 valid (block-uniform)
    const bool ybot = (y0 < 126);     // row y0+2 valid (block-uniform)
    const bool xl   = (px > 0);
    const bool xr   = (px < 127);

    for (int ci = 0; ci < 64; ci++) {
        const float* rp = x + ((size_t)(b*64 + ci)*128 + y0)*128 + px;
        // iv[r][c]: input rows y0-1+r (r=0..3), cols px-1+c (c=0..2)
        float iv[4][3];
        iv[0][0] = (ytop && xl) ? rp[-129] : 0.f;
        iv[0][1] =  ytop        ? rp[-128] : 0.f;
        iv[0][2] = (ytop && xr) ? rp[-127] : 0.f;
        iv[1][0] =  xl          ? rp[-1]   : 0.f;
        iv[1][1] =                rp[0];
        iv[1][2] =  xr          ? rp[1]    : 0.f;
        iv[2][0] =  xl          ? rp[127]  : 0.f;
        iv[2][1] =                rp[128];
        iv[2][2] =  xr          ? rp[129]  : 0.f;
        iv[3][0] = (ybot && xl) ? rp[255]  : 0.f;
        iv[3][1] =  ybot        ? rp[256]  : 0.f;
        iv[3][2] = (ybot && xr) ? rp[257]  : 0.f;

        const float* wci = wtb + __builtin_amdgcn_readfirstlane(ci*576);
        #pragma unroll
        for (int k = 0; k < 9; k++) {
            const int dy = k/3, dx = k%3;
            float v0 = iv[dy][dx];
            float v1 = iv[dy+1][dx];
            const float* wk = wci + k*64;   // uniform -> scalar loads
            #pragma unroll
            for (int c = 0; c < 64; c++) {
                float w = wk[c];
                acc0[c] += v0 * w;
                acc1[c] += v1 * w;
            }
        }
    }

    // bias + ReLU (b1 uniform -> scalar loads)
    const float* b1 = (br == 0) ? b1c : (br == 1 ? b1r : b1w);
    #pragma unroll
    for (int c = 0; c < 64; c++) {
        acc0[c] = fmaxf(acc0[c] + b1[c], 0.f);
        acc1[c] = fmaxf(acc1[c] + b1[c], 0.f);
    }

    if (br == 0) {
        float* outp = cls_o + (size_t)b*80*HWSZ + y0*128 + px;
        for (int co2 = 0; co2 < 80; co2++) {
            const float* w2row = w2c + __builtin_amdgcn_readfirstlane(co2*64);
            float s0a=0.f, s1a=0.f, s2a=0.f, s3a=0.f;
            float s0b=0.f, s1b=0.f, s2b=0.f, s3b=0.f;
            #pragma unroll
            for (int c = 0; c < 64; c += 4) {
                float w0=w2row[c+0], w1=w2row[c+1], w2v=w2row[c+2], w3=w2row[c+3];
                s0a += acc0[c+0]*w0; s1a += acc0[c+1]*w1;
                s2a += acc0[c+2]*w2v; s3a += acc0[c+3]*w3;
                s0b += acc1[c+0]*w0; s1b += acc1[c+1]*w1;
                s2b += acc1[c+2]*w2v; s3b += acc1[c+3]*w3;
            }
            float bb = b2c[co2];
            float sa = ((s0a+s1a)+(s2a+s3a)) + bb;
            float sb = ((s0b+s1b)+(s2b+s3b)) + bb;
            outp[(size_t)co2*HWSZ]       = 1.f/(1.f + expf(-sa));
            outp[(size_t)co2*HWSZ + 128] = 1.f/(1.f + expf(-sb));
        }
    } else {
        const float* w2  = (br == 1) ? w2r : w2w;
        const float* b2  = (br == 1) ? b2r : b2w;
        float* outp      = (br == 1) ? reg_o : wh_o;
        #pragma unroll
        for (int co2 = 0; co2 < 2; co2++) {
            const float* w2row = w2 + co2*64;
            float s0a=0.f, s1a=0.f, s2a=0.f, s3a=0.f;
            float s0b=0.f, s1b=0.f, s2b=0.f, s3b=0.f;
            #pragma unroll
            for (int c = 0; c < 64; c += 4) {
                float w0=w2row[c+0], w1=w2row[c+1], w2v=w2row[c+2], w3=w2row[c+3];
                s0a += acc0[c+0]*w0; s1a += acc0[c+1]*w1;
                s2a += acc0[c+2]*w2v; s3a += acc0[c+3]*w3;
                s0b += acc1[c+0]*w0; s1b += acc1[c+1]*w1;
                s2b += acc1[c+2]*w2v; s3b += acc1[c+3]*w3;
            }
            float bb = b2[co2];
            float sa = ((s0a+s1a)+(s2a+s3a)) + bb;
            float sb = ((s0b+s1b)+(s2b+s3b)) + bb;
            float oa = (br == 1) ? (1.f/(1.f + expf(-sa))) : expf(sa);
            float ob = (br == 1) ? (1.f/(1.f + expf(-sb))) : expf(sb);
            float* orow = outp + ((size_t)(b*2 + co2))*HWSZ + y0*128 + px;
            orow[0]   = oa;
            orow[128] = ob;
        }
    }
}

// ---------------------------------------------------------------------------
// Kernel 2: 3x3 peak mask + max/argmax over classes
// grid (y=128, b=16), block 128. Vertical max in regs, horizontal via LDS
// (double-buffered -> 1 barrier per class). 3 global loads/class vs 9.
// ---------------------------------------------------------------------------
__global__ void k_peaks(const float* __restrict__ cls,
                        float* __restrict__ sc, int* __restrict__ cat) {
    __shared__ float vmb[2][130];
    const int y  = blockIdx.x;
    const int b  = blockIdx.y;
    const int px = threadIdx.x;
    float best = -1.f;
    int bc = 0;
    for (int c = 0; c < 80; c++) {
        const float* pl = cls + (size_t)(b*80 + c)*HWSZ + y*128;
        float v  = pl[px];
        float t  = (y > 0)   ? pl[px - 128] : -1e30f;
        float bo = (y < 127) ? pl[px + 128] : -1e30f;
        float m3 = fmaxf(v, fmaxf(t, bo));
        float* buf = vmb[c & 1];
        buf[px + 1] = m3;
        if (px == 0)   buf[0]   = -1e30f;
        if (px == 127) buf[129] = -1e30f;
        __syncthreads();
        float m = fmaxf(buf[px], fmaxf(buf[px + 1], buf[px + 2]));
        float masked = (v == m) ? v : 0.f;
        if (masked > best) { best = masked; bc = c; }  // strict > == first-max
        // no 2nd barrier: buffer (c&1) is only rewritten at c+2, after the
        // c+1 barrier which all threads must pass having finished this read.
    }
    sc[b*HWSZ + y*128 + px]  = best;
    cat[b*HWSZ + y*128 + px] = bc;
}

// ---------------------------------------------------------------------------
// Kernel 3: fused per-batch top-100 + box decode + NMS + all outputs.
// grid 16, block 256. Destroys sc.
// ---------------------------------------------------------------------------
__global__ void k_select(float* __restrict__ sc, const int* __restrict__ cats,
                         const float* __restrict__ regp, const float* __restrict__ whp,
                         float* __restrict__ out) {
    const int b   = blockIdx.x;
    const int tid = threadIdx.x;
    float* scb = sc + (size_t)b*HWSZ;

    __shared__ float cmax[64];
    __shared__ int   cidx[64];
    __shared__ int   s_inds[KK];
    __shared__ float s_vals[KK];
    __shared__ float X1[KK], Y1[KK], X2[KK], Y2[KK], AR[KK];

    // ---- Phase A: per-chunk max (value desc, first index) ----
    {
        int c = tid >> 2, q = tid & 3;
        int base = c*256 + q*64;
        float bv = -1e30f; int bi = base;
        for (int e = 0; e < 64; e++) {
            float v = scb[base + e];
            if (v > bv) { bv = v; bi = base + e; }   // ascending: keeps first
        }
        #pragma unroll
        for (int off = 1; off <= 2; off <<= 1) {
            float ov = __shfl_xor(bv, off);
            int   oi = __shfl_xor(bi, off);
            if (ov > bv || (ov == bv && oi < bi)) { bv = ov; bi = oi; }
        }
        if (q == 0) { cmax[c] = bv; cidx[c] = bi; }
    }
    __syncthreads();

    // ---- Phase B: 100 selections, wave 0 only ----
    if (tid < 64) {
        const int l = tid;
        float v = cmax[l]; int ix = cidx[l];
        for (int it = 0; it < KK; it++) {
            float rv = v; int ri = ix;
            #pragma unroll
            for (int off = 32; off >= 1; off >>= 1) {
                float ov = __shfl_down(rv, off);
                int   oi = __shfl_down(ri, off);
                if (ov > rv || (ov == rv && oi < ri)) { rv = ov; ri = oi; }
            }
            float fv = __shfl(rv, 0);
            int   fi = __shfl(ri, 0);
            if (l == 0) { s_inds[it] = fi; s_vals[it] = fv; scb[fi] = -1e30f; }
            int wc = fi >> 8;                 // winning chunk
            int eb = wc*256 + l*4;
            float nv = -1e30f; int ni = eb;
            #pragma unroll
            for (int r = 0; r < 4; r++) {
                float u = scb[eb + r];
                if (u > nv) { nv = u; ni = eb + r; }
            }
            #pragma unroll
            for (int off = 32; off >= 1; off >>= 1) {
                float ov = __shfl_down(nv, off);
                int   oi = __shfl_down(ni, off);
                if (ov > nv || (ov == nv && oi < ni)) { nv = ov; ni = oi; }
            }
            float cv = __shfl(nv, 0);
            int   ci2 = __shfl(ni, 0);
            if (l == wc) { v = cv; ix = ci2; }
        }
    }
    __syncthreads();

    // ---- Phase C: decode boxes for the 100 selections ----
    if (tid < KK) {
        int ind   = s_inds[tid];
        float scv = s_vals[tid];
        const float* rb = regp + (size_t)b*2*HWSZ;
        const float* wb = whp  + (size_t)b*2*HWSZ;
        float r0 = rb[ind], r1 = rb[HWSZ + ind];
        float w0 = wb[ind], w1 = wb[HWSZ + ind];
        float ctx = (float)(ind & 127) + r0;
        float cty = (float)(ind >> 7) + r1;
        float x1 = (ctx - w0*0.5f)*4.f, y1 = (cty - w1*0.5f)*4.f;
        float x2 = (ctx + w0*0.5f)*4.f, y2 = (cty + w1*0.5f)*4.f;
        size_t bo = ((size_t)b*KK + tid)*4;
        out[bo+0] = x1; out[bo+1] = y1; out[bo+2] = x2; out[bo+3] = y2;
        out[BN*KK*4 + b*KK + tid]         = (float)cats[(size_t)b*HWSZ + ind];
        out[BN*KK*4 + BN*KK + b*KK + tid] = scv;
        X1[tid] = x1; Y1[tid] = y1; X2[tid] = x2; Y2[tid] = y2;
        AR[tid] = (x2 - x1)*(y2 - y1);
    }
    __syncthreads();

    // ---- Phase D: NMS in wave 0, no barriers ----
    if (tid < 64) {
        const int l = tid;
        float x1a = X1[l], y1a = Y1[l], x2a = X2[l], y2a = Y2[l], ara = AR[l];
        int   ka  = (s_vals[l] > 0.2f) ? 1 : 0;
        float x1b = 0, y1b = 0, x2b = 0, y2b = 0, arb = 0;
        int   kb  = 0;
        if (l < KK - 64) {
            x1b = X1[64+l]; y1b = Y1[64+l]; x2b = X2[64+l]; y2b = Y2[64+l];
            arb = AR[64+l];
            kb  = (s_vals[64+l] > 0.2f) ? 1 : 0;
        }
        for (int i = 0; i < KK; i++) {
            float jx1, jy1, jx2, jy2, jar; int jk;
            if (i < 64) {
                jx1 = __shfl(x1a, i); jy1 = __shfl(y1a, i);
                jx2 = __shfl(x2a, i); jy2 = __shfl(y2a, i);
                jar = __shfl(ara, i); jk  = __shfl(ka,  i);
            } else {
                int li = i - 64;
                jx1 = __shfl(x1b, li); jy1 = __shfl(y1b, li);
                jx2 = __shfl(x2b, li); jy2 = __shfl(y2b, li);
                jar = __shfl(arb, li); jk  = __shfl(kb,  li);
            }
            if (jk) {
                if (ka && l > i) {
                    float iw = fminf(jx2, x2a) - fmaxf(jx1, x1a); iw = iw > 0.f ? iw : 0.f;
                    float ih = fminf(jy2, y2a) - fmaxf(jy1, y1a); ih = ih > 0.f ? ih : 0.f;
                    float inter = iw*ih;
                    float iou = inter / (jar + ara - inter + 1e-9f);
                    if (iou > 0.5f) ka = 0;
                }
                if (kb && (64 + l) > i) {
                    float iw = fminf(jx2, x2b) - fmaxf(jx1, x1b); iw = iw > 0.f ? iw : 0.f;
                    float ih = fminf(jy2, y2b) - fmaxf(jy1, y1b); ih = ih > 0.f ? ih : 0.f;
                    float inter = iw*ih;
                    float iou = inter / (jar + arb - inter + 1e-9f);
                    if (iou > 0.5f) kb = 0;
                }
            }
        }
        int koff = BN*KK*4 + 2*BN*KK;
        out[koff + b*KK + l] = ka ? 1.f : 0.f;
        if (l < KK - 64) out[koff + b*KK + 64 + l] = kb ? 1.f : 0.f;
    }
}

// ---------------------------------------------------------------------------
extern "C" void kernel_launch(void* const* d_in, const int* in_sizes, int n_in,
                              void* d_out, int out_size, void* d_ws, size_t ws_size,
                              hipStream_t stream) {
    const float* x      = (const float*)d_in[0];
    const float* cls_w1 = (const float*)d_in[1];
    const float* cls_b1 = (const float*)d_in[2];
    const float* cls_w2 = (const float*)d_in[3];
    const float* cls_b2 = (const float*)d_in[4];
    const float* reg_w1 = (const float*)d_in[5];
    const float* reg_b1 = (const float*)d_in[6];
    const float* reg_w2 = (const float*)d_in[7];
    const float* reg_b2 = (const float*)d_in[8];
    const float* wh_w1  = (const float*)d_in[9];
    const float* wh_b1  = (const float*)d_in[10];
    const float* wh_w2  = (const float*)d_in[11];
    const float* wh_b2  = (const float*)d_in[12];

    float* ws   = (float*)d_ws;
    float* wt1  = ws + WS_WT1;
    float* clsb = ws + WS_CLS;
    float* regb = ws + WS_REG;
    float* whb  = ws + WS_WH;
    float* scw  = ws + WS_SC;
    int*   cat  = (int*)(ws + WS_CAT);
    float* out  = (float*)d_out;

    k_transpose_w1<<<(WT1_SZ + 255)/256, 256, 0, stream>>>(cls_w1, reg_w1, wh_w1, wt1);
    k_conv_branch<<<dim3(64, 16, 3), 128, 0, stream>>>(
        x, wt1, cls_b1, reg_b1, wh_b1, cls_w2, reg_w2, wh_w2,
        cls_b2, reg_b2, wh_b2, clsb, regb, whb);
    k_peaks<<<dim3(128, 16), 128, 0, stream>>>(clsb, scw, cat);
    k_select<<<16, 256, 0, stream>>>(scw, cat, regb, whb, out);
}